// Round 12
// baseline (1185.566 us; speedup 1.0000x reference)
//
#include <hip/hip_runtime.h>
#include <math.h>

// Problem constants
#define FF   81919
#define CC   16384
#define HH   512
#define NLL  2
#define GG   5
#define LAMF 0.01f

#define CH   (CC * HH)   // complex elements per state matrix

typedef short short8 __attribute__((ext_vector_type(8)));
typedef float f32x4  __attribute__((ext_vector_type(4)));

// d_out layout (float32 real parts): out[FF] | h0[CH] | h1[CH]
//
// d_ws layout (ushort units):
//   w_in_e [1024][64] | bzr0/bzr1 [2048][2048] | ba0/ba1 [1024][2048]
//   XS  [chunk][3072] bf16  (cols: 0:1024 s | 1024:2048 x | 2048:3072 rs)
//   stk [chunk][64]   bf16
//   Zbuf [chunk][1024] fp32  (sigmoided z gate, complex-interleaved)
#define W_IN_E_SZ  (1024 * 64)
#define W_ZR_SZ    (2048 * 2048)
#define W_A_SZ     (1024 * 2048)
#define W_TOTAL_SH (W_IN_E_SZ + 2 * W_ZR_SZ + 2 * W_A_SZ)   // 12648448 ushort = 25.3MB

// ---------------------------------------------------------------------------
__device__ __forceinline__ float sigmoidf_(float x) { return 1.0f / (1.0f + expf(-x)); }
__device__ __forceinline__ unsigned short f2bf(float f) {   // RNE fp32->bf16
    unsigned u = __float_as_uint(f);
    u = (u + 0x7FFF + ((u >> 16) & 1)) >> 16;
    return (unsigned short)u;
}
__device__ __forceinline__ float bf2f(unsigned short u) {
    return __uint_as_float(((unsigned)u) << 16);
}
__device__ __forceinline__ void gld_lds16(const unsigned short* g, unsigned short* l) {
    __builtin_amdgcn_global_load_lds(
        (const __attribute__((address_space(1))) void*)g,
        (__attribute__((address_space(3))) void*)l, 16, 0, 0);
}

// ---------------------------------------------------------------------------
// 0a) w_in expansion (K padded 25->32 complex, ldb=64 real)
// ---------------------------------------------------------------------------
__global__ __launch_bounds__(256) void expand_in(const float2* __restrict__ w,
                                                 unsigned short* __restrict__ Bt) {
    int i = blockIdx.x * 256 + threadIdx.x;  // [0, 512*4)
    if (i >= 512 * 4) return;
    int n = i & 511, kg = i >> 9;
    unsigned short r0[16], r1[16];
#pragma unroll
    for (int j = 0; j < 8; j++) {
        int kc = kg * 8 + j;
        float re = 0.f, im = 0.f;
        if (kc < 25) { float2 v = w[(size_t)kc * 512 + n]; re = v.x; im = v.y; }
        r0[2 * j] = f2bf(re);  r0[2 * j + 1] = f2bf(-im);
        r1[2 * j] = f2bf(im);  r1[2 * j + 1] = f2bf(re);
    }
    unsigned short* p0 = Bt + (size_t)(2 * n) * 64 + kg * 16;
    unsigned short* p1 = Bt + (size_t)(2 * n + 1) * 64 + kg * 16;
#pragma unroll
    for (int q = 0; q < 2; q++) {
        ((uint4*)p0)[q] = ((uint4*)r0)[q];
        ((uint4*)p1)[q] = ((uint4*)r1)[q];
    }
}

// ---------------------------------------------------------------------------
// 0b) paired expansion: Bt[2Nc][2048], K = [part0: src0 | part1: src1],
//     each part Kc=512 complex, src ld = 1536 complex.
// ---------------------------------------------------------------------------
__global__ __launch_bounds__(256) void expand2(const float2* __restrict__ src0,
                                               const float2* __restrict__ src1,
                                               int Nc,
                                               unsigned short* __restrict__ Bt) {
    int total = Nc * 2 * 64;
    int i = blockIdx.x * 256 + threadIdx.x;
    if (i >= total) return;
    int kg = i / (2 * Nc);
    int rem = i - kg * 2 * Nc;
    int part = rem / Nc, n = rem - part * Nc;
    const float2* src = part ? src1 : src0;
    unsigned short r0[16], r1[16];
#pragma unroll
    for (int j = 0; j < 8; j++) {
        int kc = kg * 8 + j;
        float2 v = src[(size_t)kc * 1536 + n];
        r0[2 * j] = f2bf(v.x);  r0[2 * j + 1] = f2bf(-v.y);
        r1[2 * j] = f2bf(v.y);  r1[2 * j + 1] = f2bf(v.x);
    }
    size_t ko = (size_t)part * 1024 + kg * 16;
    unsigned short* p0 = Bt + (size_t)(2 * n) * 2048 + ko;
    unsigned short* p1 = Bt + (size_t)(2 * n + 1) * 2048 + ko;
#pragma unroll
    for (int q = 0; q < 2; q++) {
        ((uint4*)p0)[q] = ((uint4*)r0)[q];
        ((uint4*)p1)[q] = ((uint4*)r1)[q];
    }
}

// ---------------------------------------------------------------------------
// 1) prep: stk[c][64] bf16 log-compressed stack (global row r0+c)
// ---------------------------------------------------------------------------
__global__ __launch_bounds__(256) void prep_kernel(const float2* __restrict__ x,
                                                   const float2* __restrict__ extras,
                                                   unsigned short* __restrict__ stk,
                                                   int r0, int m) {
    int i = blockIdx.x * 256 + threadIdx.x;
    if (i >= m * 32) return;
    int c = i >> 5, j = i & 31;
    float2 o = make_float2(0.f, 0.f);
    if (j < 25) {
        int g = j / 5, n = j - g * 5;
        int pos = (r0 + c) * 5 + g;
        float2 v = make_float2(0.f, 0.f);
        if (pos < FF) v = (n == 0) ? x[pos] : extras[(size_t)(n - 1) * FF + pos];
        float r = sqrtf(v.x * v.x + v.y * v.y);
        float sc = (r > 0.f) ? (log1pf(r) / r) : 0.f;
        o = make_float2(v.x * sc, v.y * sc);
    }
    stk[(size_t)c * 64 + 2 * j]     = f2bf(o.x);
    stk[(size_t)c * 64 + 2 * j + 1] = f2bf(o.y);
}

// ---------------------------------------------------------------------------
// 2) cvt_state: XS s-slot <- bf16(h rows)
// ---------------------------------------------------------------------------
__global__ __launch_bounds__(256) void cvt_state(const float* __restrict__ hf,
                                                 unsigned short* __restrict__ XS,
                                                 int r0, int m) {
    int i = blockIdx.x * 256 + threadIdx.x;
    if (i >= m * 128) return;
    int c = i >> 7, q = i & 127;
    const float4* s = (const float4*)(hf + (size_t)(r0 + c) * 1024 + q * 8);
    float4 a = s[0], b = s[1];
    short8 o;
    o[0] = f2bf(a.x); o[1] = f2bf(a.y); o[2] = f2bf(a.z); o[3] = f2bf(a.w);
    o[4] = f2bf(b.x); o[5] = f2bf(b.y); o[6] = f2bf(b.z); o[7] = f2bf(b.w);
    *(short8*)(XS + (size_t)c * 3072 + q * 8) = o;
}

// ---------------------------------------------------------------------------
// 3) bf16 MFMA GEMM, 128x128/BK=32, triple-buffered LDS, 2-deep prefetch,
//    counted vmcnt + raw s_barrier (T4), and T2 XOR-swizzled LDS:
//    - global source col-group pre-swizzled: s ^ ((row>>1)&3)  (rule #21)
//    - ds_read slot: rg ^ ((cl>>1)&3)
//    => 16-lane fragment reads spread over all 4 slots x 2 bank-halves
//       (2-way aliasing only, which is free per m136).
//    EPI: 0 = bf16 C out, 2 = ZR (sig z -> Zbuf, rs -> XS), 3 = A (hn -> XS+hr)
// ---------------------------------------------------------------------------
#define EPI_BF16 0
#define EPI_ZR   2
#define EPI_A    3

template <int EPI>
__global__ __launch_bounds__(256) void gemm_lds(const unsigned short* __restrict__ A, int lda,
                                                const unsigned short* __restrict__ Bt, int ldb,
                                                const float* __restrict__ bias,
                                                unsigned short* __restrict__ Cb, int ldc,
                                                float* __restrict__ Zbuf,
                                                const float* __restrict__ hf,
                                                unsigned short* __restrict__ XS,
                                                float* __restrict__ hr,
                                                int rowoff, int nk) {
    __shared__ __align__(16) unsigned short As[3][128 * 32];
    __shared__ __align__(16) unsigned short Bs[3][128 * 32];

    int t = threadIdx.x, lane = t & 63, w = t >> 6;

    // bijective 8-XCD swizzle (halves HBM fetch). nwg always %8==0.
    int nbx = gridDim.x;
    int nwg = nbx * gridDim.y;
    int id = blockIdx.y * nbx + blockIdx.x;
    int cpx = nwg >> 3;
    id = (id & 7) * cpx + (id >> 3);
    int m0 = (id / nbx) * 128, n0 = (id % nbx) * 128;

    int wr = w >> 1, wc = w & 1;
    int cl = lane & 15, rg = lane >> 4;

    // staging: lane covers (row seg_base + (lane>>2), slot lane&3); source col
    // group is slot ^ ((row>>1)&3) = (lane&3) ^ ((lane>>3)&3)  [T2 pre-swizzle]
    int lrow = lane >> 2;
    int lcol = ((lane & 3) ^ ((lane >> 3) & 3)) * 8;
    const unsigned short* Ag0 = A  + (size_t)(m0 + w * 32 + lrow) * lda + lcol;
    const unsigned short* Ag1 = A  + (size_t)(m0 + w * 32 + 16 + lrow) * lda + lcol;
    const unsigned short* Bg0 = Bt + (size_t)(n0 + w * 32 + lrow) * ldb + lcol;
    const unsigned short* Bg1 = Bt + (size_t)(n0 + w * 32 + 16 + lrow) * ldb + lcol;

    f32x4 acc[4][4] = {};

#define STAGE(buf, kt)                                        \
    do {                                                      \
        int _ko = (kt) * 32;                                  \
        gld_lds16(Ag0 + _ko, &As[buf][w * 1024]);             \
        gld_lds16(Ag1 + _ko, &As[buf][w * 1024 + 512]);       \
        gld_lds16(Bg0 + _ko, &Bs[buf][w * 1024]);             \
        gld_lds16(Bg1 + _ko, &Bs[buf][w * 1024 + 512]);       \
    } while (0)

    // prologue: 2-deep prefetch (8 outstanding loads/wave)
    STAGE(0, 0);
    STAGE(1, 1);

    // read-side swizzle key: (row>>1)&3 with row = {wr|wc}*64 + mi*16 + cl
    // -> reduces to (cl>>1)&3 (the *64 and *16 terms drop out of bits 1-2)
    int swz = (cl >> 1) & 3;
    int sA = ((rg ^ swz) * 8);

    int ib = 0, is = 2;
    for (int kt = 0; kt < nk; kt++) {
        // wait until tile kt staged: outstanding = tiles kt(4) + kt+1(4)
        if (kt < nk - 1) asm volatile("s_waitcnt vmcnt(4)" ::: "memory");
        else             asm volatile("s_waitcnt vmcnt(0)" ::: "memory");
        __builtin_amdgcn_s_barrier();   // tile-kt in LDS; recycled buffer free

        const unsigned short* Ab = As[ib];
        const unsigned short* Bb = Bs[ib];
        short8 af[4], bf[4];
#pragma unroll
        for (int mi = 0; mi < 4; mi++)
            af[mi] = *(const short8*)&Ab[(wr * 64 + mi * 16 + cl) * 32 + sA];
#pragma unroll
        for (int ni = 0; ni < 4; ni++)
            bf[ni] = *(const short8*)&Bb[(wc * 64 + ni * 16 + cl) * 32 + sA];

        if (kt + 2 < nk) STAGE(is, kt + 2);   // in flight for ~2 steps

#pragma unroll
        for (int mi = 0; mi < 4; mi++)
#pragma unroll
            for (int ni = 0; ni < 4; ni++)
                acc[mi][ni] = __builtin_amdgcn_mfma_f32_16x16x32_bf16(
                    af[mi], bf[ni], acc[mi][ni], 0, 0, 0);

        ib = (ib == 2) ? 0 : ib + 1;
        is = (is == 2) ? 0 : is + 1;
    }
#undef STAGE

    int odd = lane & 1;
#pragma unroll
    for (int ni = 0; ni < 4; ni++) {
        int col = n0 + wc * 64 + ni * 16 + cl;
        float bv = bias[col];
#pragma unroll
        for (int mi = 0; mi < 4; mi++) {
#pragma unroll
            for (int r = 0; r < 4; r++) {
                int row = m0 + wr * 64 + mi * 16 + rg * 4 + r;
                float v = acc[mi][ni][r] + bv;
                if (EPI == EPI_BF16) {
                    Cb[(size_t)row * ldc + col] = f2bf(v);
                } else if (EPI == EPI_ZR) {
                    float sv = sigmoidf_(v);
                    if (col < 1024) {
                        Zbuf[(size_t)row * 1024 + col] = sv;   // sigmoided z
                    } else {
                        float pv = __shfl_xor(sv, 1);
                        int k = (col >> 1) - 512;
                        float2 s = *(const float2*)&hf[(size_t)(rowoff + row) * 1024 + 2 * k];
                        // rs = sig(r) * s (complex); even lane = re, odd = im
                        float o = odd ? (pv * s.y + sv * s.x)
                                      : (sv * s.x - pv * s.y);
                        XS[(size_t)row * 3072 + 1024 + col] = f2bf(o);
                    }
                } else {  // EPI_A
                    float tv = tanhf(v);
                    float pt = __shfl_xor(tv, 1);
                    int k = col >> 1;
                    float2 z = *(const float2*)&Zbuf[(size_t)row * 1024 + 2 * k];
                    float2 s = *(const float2*)&hf[(size_t)(rowoff + row) * 1024 + 2 * k];
                    // hn = (1-z)*s + z*t (complex)
                    float o;
                    if (odd) o = (1.f - z.x) * s.y - z.y * s.x + z.x * tv + z.y * pt;
                    else     o = (1.f - z.x) * s.x + z.y * s.y + z.x * tv - z.y * pt;
                    XS[(size_t)row * 3072 + 1024 + col] = f2bf(o);
                    if (!odd) hr[(size_t)(rowoff + row) * 512 + k] = o;
                }
            }
        }
    }
}

// ---------------------------------------------------------------------------
// 4) output matmul: out[p] = -LAM * Re(xs_row . w_out[:,g] + b_out[g])
// ---------------------------------------------------------------------------
__global__ __launch_bounds__(256) void outmm_kernel(const unsigned short* __restrict__ XS,
                                                    const float2* __restrict__ w_out,
                                                    const float2* __restrict__ b_out,
                                                    float* __restrict__ out,
                                                    int r0, int m) {
    int wid = (blockIdx.x * 256 + threadIdx.x) >> 6;
    int lane = threadIdx.x & 63;
    if (wid >= m * GG) return;
    int c = wid / GG, g = wid - c * GG;
    const unsigned short* arow = XS + (size_t)c * 3072 + 1024;
    float ax = 0.f;
    for (int k = lane; k < HH; k += 64) {
        unsigned u = *(const unsigned*)(arow + 2 * k);
        float vx = bf2f((unsigned short)(u & 0xffff));
        float vy = bf2f((unsigned short)(u >> 16));
        float2 wv = w_out[k * GG + g];
        ax += vx * wv.x - vy * wv.y;
    }
#pragma unroll
    for (int off = 32; off > 0; off >>= 1) ax += __shfl_down(ax, off);
    if (lane == 0) {
        int p = (r0 + c) * GG + g;
        if (p < FF) out[p] = -LAMF * (ax + b_out[g].x);
    }
}

// ---------------------------------------------------------------------------
// launch
// ---------------------------------------------------------------------------
extern "C" void kernel_launch(void* const* d_in, const int* in_sizes, int n_in,
                              void* d_out, int out_size, void* d_ws, size_t ws_size,
                              hipStream_t stream) {
    const float2* x      = (const float2*)d_in[0];
    const float2* extras = (const float2*)d_in[1];
    const float2* h      = (const float2*)d_in[2];
    const float2* w_in   = (const float2*)d_in[3];
    const float2* b_in   = (const float2*)d_in[4];
    const float2* w_i    = (const float2*)d_in[5];
    const float2* w_h    = (const float2*)d_in[6];
    const float2* b_rnn  = (const float2*)d_in[7];
    const float2* w_out  = (const float2*)d_in[8];
    const float2* b_out  = (const float2*)d_in[9];

    float* outf   = (float*)d_out;        // [FF]
    float* houtr0 = outf + FF;            // [CH]
    float* houtr1 = houtr0 + (size_t)CH;  // [CH]

    unsigned short* wsh    = (unsigned short*)d_ws;
    unsigned short* w_in_e = wsh;
    unsigned short* bzr0   = w_in_e + W_IN_E_SZ;
    unsigned short* bzr1   = bzr0 + W_ZR_SZ;
    unsigned short* ba0    = bzr1 + W_ZR_SZ;
    unsigned short* ba1    = ba0 + W_A_SZ;

    // chunk: weights 25.3MB + chunk*10368B <= ws_size (~512MB available)
    size_t wbytes = (size_t)W_TOTAL_SH * 2;
    int chunk = CC;
    while (chunk > 1024 && wbytes + (size_t)chunk * 10368 > ws_size) chunk >>= 1;
    int nch = CC / chunk;

    unsigned short* XS  = ba1 + W_A_SZ;                       // [chunk*3072]
    unsigned short* stk = XS + (size_t)chunk * 3072;          // [chunk*64]
    float*          Zb  = (float*)(stk + (size_t)chunk * 64); // [chunk*1024]

    // ---- expand weights ----
    expand_in<<<(512 * 4 + 255) / 256, 256, 0, stream>>>(w_in, w_in_e);
    for (int l = 0; l < NLL; l++) {
        const float2* wil = w_i + (size_t)l * HH * 1536;
        const float2* whl = w_h + (size_t)l * HH * 1536;
        expand2<<<(1024 * 2 * 64 + 255) / 256, 256, 0, stream>>>(whl, wil, 1024, l ? bzr1 : bzr0);
        expand2<<<(512 * 2 * 64 + 255) / 256, 256, 0, stream>>>(wil + 1024, whl + 1024, 512, l ? ba1 : ba0);
    }

    for (int cb = 0; cb < nch; cb++) {
        int r0 = cb * chunk;
        int gy = chunk / 128;

        prep_kernel<<<(chunk * 32 + 255) / 256, 256, 0, stream>>>(x, extras, stk, r0, chunk);
        // x-slot = stk @ w_in + b_in  (M x 64 x 1024, bf16 -> XS+1024)
        gemm_lds<EPI_BF16><<<dim3(8, gy), 256, 0, stream>>>(
            stk, 64, w_in_e, 64, (const float*)b_in,
            XS + 1024, 3072, nullptr, nullptr, nullptr, nullptr, 0, 2);

        for (int l = 0; l < NLL; l++) {
            const float* hf = (const float*)(h + (size_t)l * CH);
            const float* bl = (const float*)(b_rnn + (size_t)l * 1536);
            float* hr = (l == 0) ? houtr0 : houtr1;
            const unsigned short* bzr = l ? bzr1 : bzr0;
            const unsigned short* ba  = l ? ba1 : ba0;

            // s-slot <- bf16(h)
            cvt_state<<<chunk * 128 / 256, 256, 0, stream>>>(hf, XS, r0, chunk);
            // ZR gemm (M x 2048 x 2048): z -> Zb (sigmoided), rs -> XS rs-slot
            gemm_lds<EPI_ZR><<<dim3(16, gy), 256, 0, stream>>>(
                XS, 3072, bzr, 2048, bl,
                nullptr, 0, Zb, hf, XS, nullptr, r0, 64);
            // A gemm (M x 1024 x 2048): hn -> XS x-slot + hr
            gemm_lds<EPI_A><<<dim3(8, gy), 256, 0, stream>>>(
                XS + 1024, 3072, ba, 2048, bl + 2048,
                nullptr, 0, Zb, hf, XS, hr, r0, 64);
        }

        outmm_kernel<<<(chunk * GG * 64 + 255) / 256, 256, 0, stream>>>(
            XS, w_out, b_out, outf, r0, chunk);
    }
}

// Round 13
// 1092.154 us; speedup vs baseline: 1.0855x; 1.0855x over previous
//
#include <hip/hip_runtime.h>
#include <math.h>

// Problem constants
#define FF   81919
#define CC   16384
#define HH   512
#define NLL  2
#define GG   5
#define LAMF 0.01f

#define CH   (CC * HH)   // complex elements per state matrix

typedef short short8 __attribute__((ext_vector_type(8)));
typedef float f32x4  __attribute__((ext_vector_type(4)));

// d_out layout (float32 real parts): out[FF] | h0[CH] | h1[CH]
//
// d_ws layout (ushort units):
//   w_in_e [1024][64] | bzr0/bzr1 [2048][2048] | ba0/ba1 [1024][2048]
//   XS  [chunk][3072] bf16  (cols: 0:1024 s | 1024:2048 x | 2048:3072 rs)
//   stk [chunk][64]   bf16
//   Zbuf [chunk][1024] fp32  (sigmoided z gate, complex-interleaved)
#define W_IN_E_SZ  (1024 * 64)
#define W_ZR_SZ    (2048 * 2048)
#define W_A_SZ     (1024 * 2048)
#define W_TOTAL_SH (W_IN_E_SZ + 2 * W_ZR_SZ + 2 * W_A_SZ)   // 12648448 ushort = 25.3MB

// ---------------------------------------------------------------------------
__device__ __forceinline__ float sigmoidf_(float x) { return 1.0f / (1.0f + expf(-x)); }
__device__ __forceinline__ unsigned short f2bf(float f) {   // RNE fp32->bf16
    unsigned u = __float_as_uint(f);
    u = (u + 0x7FFF + ((u >> 16) & 1)) >> 16;
    return (unsigned short)u;
}
__device__ __forceinline__ float bf2f(unsigned short u) {
    return __uint_as_float(((unsigned)u) << 16);
}
__device__ __forceinline__ void gld_lds16(const unsigned short* g, unsigned short* l) {
    __builtin_amdgcn_global_load_lds(
        (const __attribute__((address_space(1))) void*)g,
        (__attribute__((address_space(3))) void*)l, 16, 0, 0);
}

// ---------------------------------------------------------------------------
// 0a) w_in expansion (K padded 25->32 complex, ldb=64 real)
// ---------------------------------------------------------------------------
__global__ __launch_bounds__(256) void expand_in(const float2* __restrict__ w,
                                                 unsigned short* __restrict__ Bt) {
    int i = blockIdx.x * 256 + threadIdx.x;  // [0, 512*4)
    if (i >= 512 * 4) return;
    int n = i & 511, kg = i >> 9;
    unsigned short r0[16], r1[16];
#pragma unroll
    for (int j = 0; j < 8; j++) {
        int kc = kg * 8 + j;
        float re = 0.f, im = 0.f;
        if (kc < 25) { float2 v = w[(size_t)kc * 512 + n]; re = v.x; im = v.y; }
        r0[2 * j] = f2bf(re);  r0[2 * j + 1] = f2bf(-im);
        r1[2 * j] = f2bf(im);  r1[2 * j + 1] = f2bf(re);
    }
    unsigned short* p0 = Bt + (size_t)(2 * n) * 64 + kg * 16;
    unsigned short* p1 = Bt + (size_t)(2 * n + 1) * 64 + kg * 16;
#pragma unroll
    for (int q = 0; q < 2; q++) {
        ((uint4*)p0)[q] = ((uint4*)r0)[q];
        ((uint4*)p1)[q] = ((uint4*)r1)[q];
    }
}

// ---------------------------------------------------------------------------
// 0b) paired expansion: Bt[2Nc][2048], K = [part0: src0 | part1: src1],
//     each part Kc=512 complex, src ld = 1536 complex.
// ---------------------------------------------------------------------------
__global__ __launch_bounds__(256) void expand2(const float2* __restrict__ src0,
                                               const float2* __restrict__ src1,
                                               int Nc,
                                               unsigned short* __restrict__ Bt) {
    int total = Nc * 2 * 64;
    int i = blockIdx.x * 256 + threadIdx.x;
    if (i >= total) return;
    int kg = i / (2 * Nc);
    int rem = i - kg * 2 * Nc;
    int part = rem / Nc, n = rem - part * Nc;
    const float2* src = part ? src1 : src0;
    unsigned short r0[16], r1[16];
#pragma unroll
    for (int j = 0; j < 8; j++) {
        int kc = kg * 8 + j;
        float2 v = src[(size_t)kc * 1536 + n];
        r0[2 * j] = f2bf(v.x);  r0[2 * j + 1] = f2bf(-v.y);
        r1[2 * j] = f2bf(v.y);  r1[2 * j + 1] = f2bf(v.x);
    }
    size_t ko = (size_t)part * 1024 + kg * 16;
    unsigned short* p0 = Bt + (size_t)(2 * n) * 2048 + ko;
    unsigned short* p1 = Bt + (size_t)(2 * n + 1) * 2048 + ko;
#pragma unroll
    for (int q = 0; q < 2; q++) {
        ((uint4*)p0)[q] = ((uint4*)r0)[q];
        ((uint4*)p1)[q] = ((uint4*)r1)[q];
    }
}

// ---------------------------------------------------------------------------
// 1) prep: stk[c][64] bf16 log-compressed stack (global row r0+c)
// ---------------------------------------------------------------------------
__global__ __launch_bounds__(256) void prep_kernel(const float2* __restrict__ x,
                                                   const float2* __restrict__ extras,
                                                   unsigned short* __restrict__ stk,
                                                   int r0, int m) {
    int i = blockIdx.x * 256 + threadIdx.x;
    if (i >= m * 32) return;
    int c = i >> 5, j = i & 31;
    float2 o = make_float2(0.f, 0.f);
    if (j < 25) {
        int g = j / 5, n = j - g * 5;
        int pos = (r0 + c) * 5 + g;
        float2 v = make_float2(0.f, 0.f);
        if (pos < FF) v = (n == 0) ? x[pos] : extras[(size_t)(n - 1) * FF + pos];
        float r = sqrtf(v.x * v.x + v.y * v.y);
        float sc = (r > 0.f) ? (log1pf(r) / r) : 0.f;
        o = make_float2(v.x * sc, v.y * sc);
    }
    stk[(size_t)c * 64 + 2 * j]     = f2bf(o.x);
    stk[(size_t)c * 64 + 2 * j + 1] = f2bf(o.y);
}

// ---------------------------------------------------------------------------
// 2) cvt_state: XS s-slot <- bf16(h rows)
// ---------------------------------------------------------------------------
__global__ __launch_bounds__(256) void cvt_state(const float* __restrict__ hf,
                                                 unsigned short* __restrict__ XS,
                                                 int r0, int m) {
    int i = blockIdx.x * 256 + threadIdx.x;
    if (i >= m * 128) return;
    int c = i >> 7, q = i & 127;
    const float4* s = (const float4*)(hf + (size_t)(r0 + c) * 1024 + q * 8);
    float4 a = s[0], b = s[1];
    short8 o;
    o[0] = f2bf(a.x); o[1] = f2bf(a.y); o[2] = f2bf(a.z); o[3] = f2bf(a.w);
    o[4] = f2bf(b.x); o[5] = f2bf(b.y); o[6] = f2bf(b.z); o[7] = f2bf(b.w);
    *(short8*)(XS + (size_t)c * 3072 + q * 8) = o;
}

// ---------------------------------------------------------------------------
// 3) 256x256 phase-split bf16 MFMA GEMM (BK=32, 8 waves 2Mx4N, 512 thr).
//    - 4 LDS buffers (128KB): tile t in buf t&3; tile t+3 staged during t.
//    - counted vmcnt at tile start only: 8 steady / 4 / 0 at the tail.
//    - 2 phases per tile, raw s_barrier, setprio around MFMA cluster (T5).
//    - R12-verified zero-conflict LDS slot swizzle on both sides (T2).
//    EPI: 0 = bf16 C out, 2 = ZR (sig z -> Zbuf, rs -> XS), 3 = A (hn -> XS+hr)
// ---------------------------------------------------------------------------
#define EPI_BF16 0
#define EPI_ZR   2
#define EPI_A    3

template <int EPI>
__global__ __launch_bounds__(512, 2) void gemm256(const unsigned short* __restrict__ A, int lda,
                                                  const unsigned short* __restrict__ Bt, int ldb,
                                                  const float* __restrict__ bias,
                                                  unsigned short* __restrict__ Cb, int ldc,
                                                  float* __restrict__ Zbuf,
                                                  const float* __restrict__ hf,
                                                  unsigned short* __restrict__ XS,
                                                  float* __restrict__ hr,
                                                  int rowoff, int nk) {
    __shared__ __align__(16) unsigned short LA[4][8192];   // 4 x [256][32]
    __shared__ __align__(16) unsigned short LB[4][8192];

    int t = threadIdx.x, lane = t & 63, w = t >> 6;        // w 0..7

    // bijective 8-XCD swizzle (nwg always %8==0)
    int nbx = gridDim.x;
    int nwg = nbx * gridDim.y;
    int id = blockIdx.y * nbx + blockIdx.x;
    int cpx = nwg >> 3;
    id = (id & 7) * cpx + (id >> 3);
    int m0 = (id / nbx) * 256, n0 = (id % nbx) * 256;

    int wr = w >> 2, wc = w & 3;                           // 2M x 4N wave grid
    int cl = lane & 15, rg = lane >> 4;

    // staging: wave w covers rows w*32..w*32+31 of A-tile and B-tile
    // (2 x 16-row 1KB segments each). lane l -> row +(l>>2), src slot
    // pre-swizzled (l&3)^((l>>3)&3)  [R12-verified]
    int lrow = lane >> 2;
    int lcol = ((lane & 3) ^ ((lane >> 3) & 3)) * 8;
    const unsigned short* AgS0 = A  + (size_t)(m0 + w * 32 + lrow) * lda + lcol;
    const unsigned short* AgS1 = A  + (size_t)(m0 + w * 32 + 16 + lrow) * lda + lcol;
    const unsigned short* BgS0 = Bt + (size_t)(n0 + w * 32 + lrow) * ldb + lcol;
    const unsigned short* BgS1 = Bt + (size_t)(n0 + w * 32 + 16 + lrow) * ldb + lcol;

#define STAGE_A(b, j) do { int _o = (j) * 32;                         \
        gld_lds16(AgS0 + _o, &LA[b][w * 1024]);                        \
        gld_lds16(AgS1 + _o, &LA[b][w * 1024 + 512]); } while (0)
#define STAGE_B(b, j) do { int _o = (j) * 32;                         \
        gld_lds16(BgS0 + _o, &LB[b][w * 1024]);                        \
        gld_lds16(BgS1 + _o, &LB[b][w * 1024 + 512]); } while (0)

    // prologue: stage tiles 0..2 (4 loads/wave each)
    if (nk > 0) { STAGE_A(0, 0); STAGE_B(0, 0); }
    if (nk > 1) { STAGE_A(1, 1); STAGE_B(1, 1); }
    if (nk > 2) { STAGE_A(2, 2); STAGE_B(2, 2); }

    // read-side swizzle (R12-verified): slot = rg ^ ((cl>>1)&3)
    int sA = (rg ^ ((cl >> 1) & 3)) * 8;

    f32x4 acc[8][4] = {};

    for (int kt = 0; kt < nk; kt++) {
        // tile kt landed iff outstanding <= (loads of tiles kt+1, kt+2)
        if (kt < nk - 2)       asm volatile("s_waitcnt vmcnt(8)" ::: "memory");
        else if (kt == nk - 2) asm volatile("s_waitcnt vmcnt(4)" ::: "memory");
        else                   asm volatile("s_waitcnt vmcnt(0)" ::: "memory");
        __builtin_amdgcn_s_barrier();      // all waves' tile-kt stages visible

        int b = kt & 3;
        const unsigned short* Ab = LA[b];
        const unsigned short* Bb = LB[b];

        // ---- phase 0: frags (4b + 4a) | stage A of kt+3 | MFMA m0..3 ----
        short8 bf[4], af[4];
#pragma unroll
        for (int ni = 0; ni < 4; ni++)
            bf[ni] = *(const short8*)&Bb[(wc * 64 + ni * 16 + cl) * 32 + sA];
#pragma unroll
        for (int mi = 0; mi < 4; mi++)
            af[mi] = *(const short8*)&Ab[(wr * 128 + mi * 16 + cl) * 32 + sA];
        if (kt + 3 < nk) STAGE_A((kt + 3) & 3, kt + 3);
        __builtin_amdgcn_s_barrier();
        __builtin_amdgcn_s_setprio(1);
#pragma unroll
        for (int mi = 0; mi < 4; mi++)
#pragma unroll
            for (int ni = 0; ni < 4; ni++)
                acc[mi][ni] = __builtin_amdgcn_mfma_f32_16x16x32_bf16(
                    af[mi], bf[ni], acc[mi][ni], 0, 0, 0);
        __builtin_amdgcn_s_setprio(0);
        __builtin_amdgcn_s_barrier();

        // ---- phase 1: frags (4a) | stage B of kt+3 | MFMA m4..7 ----
#pragma unroll
        for (int mi = 0; mi < 4; mi++)
            af[mi] = *(const short8*)&Ab[(wr * 128 + (mi + 4) * 16 + cl) * 32 + sA];
        if (kt + 3 < nk) STAGE_B((kt + 3) & 3, kt + 3);
        __builtin_amdgcn_s_barrier();
        __builtin_amdgcn_s_setprio(1);
#pragma unroll
        for (int mi = 0; mi < 4; mi++)
#pragma unroll
            for (int ni = 0; ni < 4; ni++)
                acc[mi + 4][ni] = __builtin_amdgcn_mfma_f32_16x16x32_bf16(
                    af[mi], bf[ni], acc[mi + 4][ni], 0, 0, 0);
        __builtin_amdgcn_s_setprio(0);
        // next iteration's vmcnt+barrier closes this tile
    }
#undef STAGE_A
#undef STAGE_B

    int odd = lane & 1;
#pragma unroll
    for (int ni = 0; ni < 4; ni++) {
        int col = n0 + wc * 64 + ni * 16 + cl;
        float bv = bias[col];
#pragma unroll
        for (int mi = 0; mi < 8; mi++) {
#pragma unroll
            for (int r = 0; r < 4; r++) {
                int row = m0 + wr * 128 + mi * 16 + rg * 4 + r;
                float v = acc[mi][ni][r] + bv;
                if (EPI == EPI_BF16) {
                    Cb[(size_t)row * ldc + col] = f2bf(v);
                } else if (EPI == EPI_ZR) {
                    float sv = sigmoidf_(v);
                    if (col < 1024) {
                        Zbuf[(size_t)row * 1024 + col] = sv;   // sigmoided z
                    } else {
                        float pv = __shfl_xor(sv, 1);
                        int k = (col >> 1) - 512;
                        float2 s = *(const float2*)&hf[(size_t)(rowoff + row) * 1024 + 2 * k];
                        // rs = sig(r) * s (complex); even lane = re, odd = im
                        float o = odd ? (pv * s.y + sv * s.x)
                                      : (sv * s.x - pv * s.y);
                        XS[(size_t)row * 3072 + 1024 + col] = f2bf(o);
                    }
                } else {  // EPI_A
                    float tv = tanhf(v);
                    float pt = __shfl_xor(tv, 1);
                    int k = col >> 1;
                    float2 z = *(const float2*)&Zbuf[(size_t)row * 1024 + 2 * k];
                    float2 s = *(const float2*)&hf[(size_t)(rowoff + row) * 1024 + 2 * k];
                    // hn = (1-z)*s + z*t (complex)
                    float o;
                    if (odd) o = (1.f - z.x) * s.y - z.y * s.x + z.x * tv + z.y * pt;
                    else     o = (1.f - z.x) * s.x + z.y * s.y + z.x * tv - z.y * pt;
                    XS[(size_t)row * 3072 + 1024 + col] = f2bf(o);
                    if (!odd) hr[(size_t)(rowoff + row) * 512 + k] = o;
                }
            }
        }
    }
}

// ---------------------------------------------------------------------------
// 4) output matmul: out[p] = -LAM * Re(xs_row . w_out[:,g] + b_out[g])
// ---------------------------------------------------------------------------
__global__ __launch_bounds__(256) void outmm_kernel(const unsigned short* __restrict__ XS,
                                                    const float2* __restrict__ w_out,
                                                    const float2* __restrict__ b_out,
                                                    float* __restrict__ out,
                                                    int r0, int m) {
    int wid = (blockIdx.x * 256 + threadIdx.x) >> 6;
    int lane = threadIdx.x & 63;
    if (wid >= m * GG) return;
    int c = wid / GG, g = wid - c * GG;
    const unsigned short* arow = XS + (size_t)c * 3072 + 1024;
    float ax = 0.f;
    for (int k = lane; k < HH; k += 64) {
        unsigned u = *(const unsigned*)(arow + 2 * k);
        float vx = bf2f((unsigned short)(u & 0xffff));
        float vy = bf2f((unsigned short)(u >> 16));
        float2 wv = w_out[k * GG + g];
        ax += vx * wv.x - vy * wv.y;
    }
#pragma unroll
    for (int off = 32; off > 0; off >>= 1) ax += __shfl_down(ax, off);
    if (lane == 0) {
        int p = (r0 + c) * GG + g;
        if (p < FF) out[p] = -LAMF * (ax + b_out[g].x);
    }
}

// ---------------------------------------------------------------------------
// launch
// ---------------------------------------------------------------------------
extern "C" void kernel_launch(void* const* d_in, const int* in_sizes, int n_in,
                              void* d_out, int out_size, void* d_ws, size_t ws_size,
                              hipStream_t stream) {
    const float2* x      = (const float2*)d_in[0];
    const float2* extras = (const float2*)d_in[1];
    const float2* h      = (const float2*)d_in[2];
    const float2* w_in   = (const float2*)d_in[3];
    const float2* b_in   = (const float2*)d_in[4];
    const float2* w_i    = (const float2*)d_in[5];
    const float2* w_h    = (const float2*)d_in[6];
    const float2* b_rnn  = (const float2*)d_in[7];
    const float2* w_out  = (const float2*)d_in[8];
    const float2* b_out  = (const float2*)d_in[9];

    float* outf   = (float*)d_out;        // [FF]
    float* houtr0 = outf + FF;            // [CH]
    float* houtr1 = houtr0 + (size_t)CH;  // [CH]

    unsigned short* wsh    = (unsigned short*)d_ws;
    unsigned short* w_in_e = wsh;
    unsigned short* bzr0   = w_in_e + W_IN_E_SZ;
    unsigned short* bzr1   = bzr0 + W_ZR_SZ;
    unsigned short* ba0    = bzr1 + W_ZR_SZ;
    unsigned short* ba1    = ba0 + W_A_SZ;

    // chunk: weights 25.3MB + chunk*10368B <= ws_size (~512MB available)
    size_t wbytes = (size_t)W_TOTAL_SH * 2;
    int chunk = CC;
    while (chunk > 1024 && wbytes + (size_t)chunk * 10368 > ws_size) chunk >>= 1;
    int nch = CC / chunk;

    unsigned short* XS  = ba1 + W_A_SZ;                       // [chunk*3072]
    unsigned short* stk = XS + (size_t)chunk * 3072;          // [chunk*64]
    float*          Zb  = (float*)(stk + (size_t)chunk * 64); // [chunk*1024]

    // ---- expand weights ----
    expand_in<<<(512 * 4 + 255) / 256, 256, 0, stream>>>(w_in, w_in_e);
    for (int l = 0; l < NLL; l++) {
        const float2* wil = w_i + (size_t)l * HH * 1536;
        const float2* whl = w_h + (size_t)l * HH * 1536;
        expand2<<<(1024 * 2 * 64 + 255) / 256, 256, 0, stream>>>(whl, wil, 1024, l ? bzr1 : bzr0);
        expand2<<<(512 * 2 * 64 + 255) / 256, 256, 0, stream>>>(wil + 1024, whl + 1024, 512, l ? ba1 : ba0);
    }

    for (int cb = 0; cb < nch; cb++) {
        int r0 = cb * chunk;
        int gy = chunk / 256;

        prep_kernel<<<(chunk * 32 + 255) / 256, 256, 0, stream>>>(x, extras, stk, r0, chunk);
        // x-slot = stk @ w_in + b_in  (M x 64 x 1024, bf16 -> XS+1024, nk=2)
        gemm256<EPI_BF16><<<dim3(4, gy), 512, 0, stream>>>(
            stk, 64, w_in_e, 64, (const float*)b_in,
            XS + 1024, 3072, nullptr, nullptr, nullptr, nullptr, 0, 2);

        for (int l = 0; l < NLL; l++) {
            const float* hf = (const float*)(h + (size_t)l * CH);
            const float* bl = (const float*)(b_rnn + (size_t)l * 1536);
            float* hr = (l == 0) ? houtr0 : houtr1;
            const unsigned short* bzr = l ? bzr1 : bzr0;
            const unsigned short* ba  = l ? ba1 : ba0;

            // s-slot <- bf16(h)
            cvt_state<<<chunk * 128 / 256, 256, 0, stream>>>(hf, XS, r0, chunk);
            // ZR gemm (M x 2048 x 2048): z -> Zb (sigmoided), rs -> XS rs-slot
            gemm256<EPI_ZR><<<dim3(8, gy), 512, 0, stream>>>(
                XS, 3072, bzr, 2048, bl,
                nullptr, 0, Zb, hf, XS, nullptr, r0, 64);
            // A gemm (M x 1024 x 2048): hn -> XS x-slot + hr
            gemm256<EPI_A><<<dim3(4, gy), 512, 0, stream>>>(
                XS + 1024, 3072, ba, 2048, bl + 2048,
                nullptr, 0, Zb, hf, XS, hr, r0, 64);
        }

        outmm_kernel<<<(chunk * GG * 64 + 255) / 256, 256, 0, stream>>>(
            XS, w_out, b_out, outf, r0, chunk);
    }
}